// Round 2
// baseline (393.464 us; speedup 1.0000x reference)
//
#include <hip/hip_runtime.h>

// Fused chunked causal attention + RoPE for MI355X (gfx950).
// B=4, SLEN=4096, H=8, ZD=128, VD=256, CHUNK=1024  -> 16 chunks x 8 heads.
// fp32 in/out; internal fp16 MFMA (16x16x32) with fp32 accumulation.

#define NHEAD 8
#define ZDIM  128
#define VDIM  256
#define CHUNK 1024
#define QT    128   // q rows per block
#define KT    64    // k rows per tile
#define NW    8     // waves per block

typedef _Float16 f16x8 __attribute__((ext_vector_type(8)));
typedef _Float16 f16x4 __attribute__((ext_vector_type(4)));
typedef float    f32x4 __attribute__((ext_vector_type(4)));

#define KSTRIDE 136   // halfs per K-lds row (128 + 8 pad)
#define VSTRIDE 72    // halfs per V^T-lds row (64 + 8 pad)
#define PSTRIDE 72    // halfs per P-lds row  (64 + 8 pad)

__global__ __launch_bounds__(512, 2)
void attn_fused(const float* __restrict__ xq, const float* __restrict__ xk,
                const float* __restrict__ xv, const float* __restrict__ cosT,
                const float* __restrict__ sinT, float* __restrict__ out)
{
  __shared__ _Float16 Klds[KT * KSTRIDE];        // K tile, row-major [k][d]
  __shared__ _Float16 Vlds[VDIM * VSTRIDE];      // V tile, transposed [vcol][k] (k-blocks XOR-swizzled)
  __shared__ _Float16 Plds[NW * 16 * PSTRIDE];   // per-wave P re-layout buffer

  const int qt = 7 - (int)blockIdx.x;     // heavy tiles first
  const int ch = blockIdx.y;              // 0..127
  const int h  = ch & 7;
  const int cb = ch >> 3;                 // chunk id 0..15

  const int tid  = threadIdx.x;
  const int w    = tid >> 6;              // wave 0..7
  const int lane = tid & 63;
  const int l15  = lane & 15;
  const int lhi  = lane >> 4;             // 0..3

  const size_t row0 = (size_t)cb * CHUNK; // first global row of this chunk

  // ---- Q tile -> registers (RoPE'd, fp16 A-frags). wave w owns rows [w*16, w*16+16) ----
  const int qrow = qt * QT + w * 16 + l15;             // row within chunk (== RoPE position)
  const float* qp = xq + (row0 + qrow) * (size_t)(NHEAD * ZDIM) + h * ZDIM;
  const float* cq = cosT + qrow * (ZDIM / 2);
  const float* sq = sinT + qrow * (ZDIM / 2);
  f16x8 qfrag[4];
#pragma unroll
  for (int blk = 0; blk < 4; ++blk) {
    const int d0 = blk * 32 + lhi * 8;
    float4 a  = *(const float4*)(qp + d0);
    float4 bb = *(const float4*)(qp + d0 + 4);
    float xs[8] = {a.x, a.y, a.z, a.w, bb.x, bb.y, bb.z, bb.w};
    f16x8 fr;
#pragma unroll
    for (int p = 0; p < 4; ++p) {
      const float cv = cq[(d0 >> 1) + p];
      const float sv = sq[(d0 >> 1) + p];
      const float xr = xs[2 * p], xi = xs[2 * p + 1];
      fr[2 * p]     = (_Float16)(xr * cv - xi * sv);
      fr[2 * p + 1] = (_Float16)(xr * sv + xi * cv);
    }
    qfrag[blk] = fr;
  }

  const f32x4 zf = {0.f, 0.f, 0.f, 0.f};
  f32x4 acc[16];
#pragma unroll
  for (int i = 0; i < 16; ++i) acc[i] = zf;
  float mrun[4] = {-3e38f, -3e38f, -3e38f, -3e38f};
  float lrun[4] = {0.f, 0.f, 0.f, 0.f};

  const int nkt = 2 * qt + 2;

  // staging index precompute
  const int kr  = tid >> 3;               // K row 0..63
  const int kc0 = (tid & 7) * 16;         // K col group (16 cols)
  const int vg  = tid >> 5;               // 0..15 -> V rows vg*4..+3
  const int vc0 = (tid & 31) * 8;         // V col group (8 cols)
  const int vsw = tid & 7;                // XOR swizzle = (c>>3)&7 for c in [vc0, vc0+8)

  for (int kt = 0; kt < nkt; ++kt) {
    __syncthreads();   // previous iteration's LDS reads complete before overwrite

    // ---- stage K tile with RoPE: Klds[k][d] ----
    {
      const int krow = kt * KT + kr;
      const float* kp = xk + (row0 + krow) * (size_t)(NHEAD * ZDIM) + h * ZDIM + kc0;
      const float* ck = cosT + krow * (ZDIM / 2) + (kc0 >> 1);
      const float* sk = sinT + krow * (ZDIM / 2) + (kc0 >> 1);
      float bufv[16];
#pragma unroll
      for (int i = 0; i < 4; ++i) {
        float4 t = *(const float4*)(kp + i * 4);
        bufv[4 * i] = t.x; bufv[4 * i + 1] = t.y; bufv[4 * i + 2] = t.z; bufv[4 * i + 3] = t.w;
      }
      f16x8 o0, o1;
#pragma unroll
      for (int p = 0; p < 8; ++p) {
        const float cv = ck[p], sv = sk[p];
        const float xr = bufv[2 * p], xi = bufv[2 * p + 1];
        const float orr = xr * cv - xi * sv;
        const float oii = xr * sv + xi * cv;
        if (p < 4) { o0[2 * p] = (_Float16)orr; o0[2 * p + 1] = (_Float16)oii; }
        else       { o1[2 * (p - 4)] = (_Float16)orr; o1[2 * (p - 4) + 1] = (_Float16)oii; }
      }
      *(f16x8*)&Klds[kr * KSTRIDE + kc0]     = o0;
      *(f16x8*)&Klds[kr * KSTRIDE + kc0 + 8] = o1;
    }

    // ---- stage V tile transposed: Vlds[vcol][k], k-blocks (8 halfs) XOR-swizzled by (vcol>>3)&7 ----
    {
      const int vrow = kt * KT + vg * 4;
      const float* vp = xv + (row0 + vrow) * (size_t)(NHEAD * VDIM) + h * VDIM + vc0;
      f16x4 t4[8];
#pragma unroll
      for (int rr = 0; rr < 4; ++rr) {
        float4 v0 = *(const float4*)(vp + (size_t)rr * (NHEAD * VDIM));
        float4 v1 = *(const float4*)(vp + (size_t)rr * (NHEAD * VDIM) + 4);
        t4[0][rr] = (_Float16)v0.x; t4[1][rr] = (_Float16)v0.y;
        t4[2][rr] = (_Float16)v0.z; t4[3][rr] = (_Float16)v0.w;
        t4[4][rr] = (_Float16)v1.x; t4[5][rr] = (_Float16)v1.y;
        t4[6][rr] = (_Float16)v1.z; t4[7][rr] = (_Float16)v1.w;
      }
      const int kblk = vg >> 1;
      const int inb  = (vg & 1) * 4;
#pragma unroll
      for (int ci = 0; ci < 8; ++ci) {
        const int c = vc0 + ci;
        *(f16x4*)&Vlds[c * VSTRIDE + ((kblk ^ vsw) * 8) + inb] = t4[ci];
      }
    }
    __syncthreads();

    // ---- S = Q K^T  (wave: 16 q-rows x 64 k-cols) ----
    f32x4 sfrag[4];
#pragma unroll
    for (int n = 0; n < 4; ++n) sfrag[n] = zf;
#pragma unroll
    for (int n = 0; n < 4; ++n) {
#pragma unroll
      for (int blk = 0; blk < 4; ++blk) {
        f16x8 bfr = *(const f16x8*)&Klds[(n * 16 + l15) * KSTRIDE + blk * 32 + lhi * 8];
        sfrag[n] = __builtin_amdgcn_mfma_f32_16x16x32_f16(qfrag[blk], bfr, sfrag[n], 0, 0, 0);
      }
    }

    // ---- causal mask on diagonal tiles ----
    if (kt >= 2 * qt) {
      const int qg = qt * QT + w * 16 + lhi * 4;  // row of reg 0
#pragma unroll
      for (int n = 0; n < 4; ++n) {
        const int kg = kt * KT + n * 16 + l15;
#pragma unroll
        for (int r = 0; r < 4; ++r)
          if (kg > qg + r) sfrag[n][r] = -1.0e9f;
      }
    }

    // ---- online softmax (row = lhi*4 + r, spread over 16 lanes x 4 frags) ----
    float pvv[4][4];
#pragma unroll
    for (int r = 0; r < 4; ++r) {
      float mx = fmaxf(fmaxf(sfrag[0][r], sfrag[1][r]), fmaxf(sfrag[2][r], sfrag[3][r]));
      mx = fmaxf(mx, __shfl_xor(mx, 1));
      mx = fmaxf(mx, __shfl_xor(mx, 2));
      mx = fmaxf(mx, __shfl_xor(mx, 4));
      mx = fmaxf(mx, __shfl_xor(mx, 8));
      const float Mn = fmaxf(mrun[r], mx);
      const float al = __expf(mrun[r] - Mn);
      mrun[r] = Mn;
      float ls = 0.f;
#pragma unroll
      for (int n = 0; n < 4; ++n) {
        const float p = __expf(sfrag[n][r] - Mn);
        pvv[n][r] = p;
        ls += p;
      }
      ls += __shfl_xor(ls, 1);
      ls += __shfl_xor(ls, 2);
      ls += __shfl_xor(ls, 4);
      ls += __shfl_xor(ls, 8);
      lrun[r] = lrun[r] * al + ls;
#pragma unroll
      for (int i = 0; i < 16; ++i) acc[i][r] *= al;
    }

    // ---- P -> LDS (re-layout D-frag -> A-frag) ----
#pragma unroll
    for (int n = 0; n < 4; ++n)
#pragma unroll
      for (int r = 0; r < 4; ++r)
        Plds[(w * 16 + lhi * 4 + r) * PSTRIDE + n * 16 + l15] = (_Float16)pvv[n][r];
    __syncthreads();   // canonical barrier: P writes visible before PV reads

    // ---- O += P V ----
#pragma unroll
    for (int kb = 0; kb < 2; ++kb) {
      f16x8 afr = *(const f16x8*)&Plds[(w * 16 + l15) * PSTRIDE + kb * 32 + lhi * 8];
#pragma unroll
      for (int i = 0; i < 16; ++i) {
        const int vcol = i * 16 + l15;
        f16x8 bfr = *(const f16x8*)&Vlds[vcol * VSTRIDE + (((kb * 4 + lhi) ^ ((vcol >> 3) & 7)) * 8)];
        acc[i] = __builtin_amdgcn_mfma_f32_16x16x32_f16(afr, bfr, acc[i], 0, 0, 0);
      }
    }
  }

  // ---- epilogue: divide by softmax denom, store fp32 ----
  const size_t obase = (row0 + (size_t)qt * QT + w * 16) * (size_t)(NHEAD * VDIM) + h * VDIM;
#pragma unroll
  for (int i = 0; i < 16; ++i) {
#pragma unroll
    for (int r = 0; r < 4; ++r) {
      const int q = lhi * 4 + r;
      out[obase + (size_t)q * (NHEAD * VDIM) + i * 16 + l15] = acc[i][r] / lrun[r];
    }
  }
}

extern "C" void kernel_launch(void* const* d_in, const int* in_sizes, int n_in,
                              void* d_out, int out_size, void* d_ws, size_t ws_size,
                              hipStream_t stream) {
  const float* xq   = (const float*)d_in[0];
  const float* xk   = (const float*)d_in[1];
  const float* xv   = (const float*)d_in[2];
  // d_in[3] = mask (unused: causal mask computed analytically)
  const float* cosT = (const float*)d_in[4];
  const float* sinT = (const float*)d_in[5];
  float* out = (float*)d_out;

  dim3 grid(8, 128);   // q-tiles x (chunk*head)
  dim3 block(512);
  attn_fused<<<grid, block, 0, stream>>>(xq, xk, xv, cosT, sinT, out);
}

// Round 3
// 256.006 us; speedup vs baseline: 1.5369x; 1.5369x over previous
//
#include <hip/hip_runtime.h>

// Fused chunked causal attention + RoPE for MI355X (gfx950).
// B=4, SLEN=4096, H=8, ZD=128, VD=256, CHUNK=1024  -> 16 chunks x 8 heads.
// fp32 in/out; internal fp16 MFMA (16x16x32) with fp32 accumulation.
// Round 3: balanced q-tile pairing (qt, 7-qt) -> 512 identical blocks (18 k-tiles each),
// exactly 2 blocks/CU, no straggler tail.

#define NHEAD 8
#define ZDIM  128
#define VDIM  256
#define CHUNK 1024
#define QT    128   // q rows per q-tile
#define KT    64    // k rows per tile
#define NW    8     // waves per block

typedef _Float16 f16x8 __attribute__((ext_vector_type(8)));
typedef _Float16 f16x4 __attribute__((ext_vector_type(4)));
typedef float    f32x4 __attribute__((ext_vector_type(4)));

#define KSTRIDE 136   // halfs per K-lds row (128 + 8 pad)
#define VSTRIDE 72    // halfs per V^T-lds row (64 + 8 pad)
#define PSTRIDE 72    // halfs per P-lds row  (64 + 8 pad)

__global__ __launch_bounds__(512, 2)
void attn_fused(const float* __restrict__ xq, const float* __restrict__ xk,
                const float* __restrict__ xv, const float* __restrict__ cosT,
                const float* __restrict__ sinT, float* __restrict__ out)
{
  __shared__ _Float16 Klds[KT * KSTRIDE];        // K tile, row-major [k][d]
  __shared__ _Float16 Vlds[VDIM * VSTRIDE];      // V tile, transposed [vcol][k] (k-blocks XOR-swizzled)
  __shared__ _Float16 Plds[NW * 16 * PSTRIDE];   // per-wave P re-layout buffer

  const int qpair = (int)blockIdx.x;      // 0..3 -> handles q-tiles {7-qpair, qpair}
  const int ch = blockIdx.y;              // 0..127
  const int h  = ch & 7;
  const int cb = ch >> 3;                 // chunk id 0..15

  const int tid  = threadIdx.x;
  const int w    = tid >> 6;              // wave 0..7
  const int lane = tid & 63;
  const int l15  = lane & 15;
  const int lhi  = lane >> 4;             // 0..3

  const size_t row0 = (size_t)cb * CHUNK; // first global row of this chunk

  // staging index precompute (loop-invariant)
  const int kr  = tid >> 3;               // K row 0..63
  const int kc0 = (tid & 7) * 16;         // K col group (16 cols)
  const int vg  = tid >> 5;               // 0..15 -> V rows vg*4..+3
  const int vc0 = (tid & 31) * 8;         // V col group (8 cols)
  const int vsw = tid & 7;                // XOR swizzle = (c>>3)&7 for c in [vc0, vc0+8)

  for (int half = 0; half < 2; ++half) {
    const int qt = half ? qpair : (7 - qpair);   // heavy q-tile first

    // ---- Q tile -> registers (RoPE'd, fp16 A-frags). wave w owns rows [w*16, w*16+16) ----
    const int qrow = qt * QT + w * 16 + l15;           // row within chunk (== RoPE position)
    const float* qp = xq + (row0 + qrow) * (size_t)(NHEAD * ZDIM) + h * ZDIM;
    const float* cq = cosT + qrow * (ZDIM / 2);
    const float* sq = sinT + qrow * (ZDIM / 2);
    f16x8 qfrag[4];
#pragma unroll
    for (int blk = 0; blk < 4; ++blk) {
      const int d0 = blk * 32 + lhi * 8;
      float4 a  = *(const float4*)(qp + d0);
      float4 bb = *(const float4*)(qp + d0 + 4);
      float xs[8] = {a.x, a.y, a.z, a.w, bb.x, bb.y, bb.z, bb.w};
      f16x8 fr;
#pragma unroll
      for (int p = 0; p < 4; ++p) {
        const float cv = cq[(d0 >> 1) + p];
        const float sv = sq[(d0 >> 1) + p];
        const float xr = xs[2 * p], xi = xs[2 * p + 1];
        fr[2 * p]     = (_Float16)(xr * cv - xi * sv);
        fr[2 * p + 1] = (_Float16)(xr * sv + xi * cv);
      }
      qfrag[blk] = fr;
    }

    const f32x4 zf = {0.f, 0.f, 0.f, 0.f};
    f32x4 acc[16];
#pragma unroll
    for (int i = 0; i < 16; ++i) acc[i] = zf;
    float mrun[4] = {-3e38f, -3e38f, -3e38f, -3e38f};
    float lrun[4] = {0.f, 0.f, 0.f, 0.f};

    const int nkt = 2 * qt + 2;

    for (int kt = 0; kt < nkt; ++kt) {
      __syncthreads();   // previous iteration's (or previous q-tile's) LDS reads complete

      // ---- stage K tile with RoPE: Klds[k][d] ----
      {
        const int krow = kt * KT + kr;
        const float* kp = xk + (row0 + krow) * (size_t)(NHEAD * ZDIM) + h * ZDIM + kc0;
        const float* ck = cosT + krow * (ZDIM / 2) + (kc0 >> 1);
        const float* sk = sinT + krow * (ZDIM / 2) + (kc0 >> 1);
        float bufv[16];
#pragma unroll
        for (int i = 0; i < 4; ++i) {
          float4 t = *(const float4*)(kp + i * 4);
          bufv[4 * i] = t.x; bufv[4 * i + 1] = t.y; bufv[4 * i + 2] = t.z; bufv[4 * i + 3] = t.w;
        }
        f16x8 o0, o1;
#pragma unroll
        for (int p = 0; p < 8; ++p) {
          const float cv = ck[p], sv = sk[p];
          const float xr = bufv[2 * p], xi = bufv[2 * p + 1];
          const float orr = xr * cv - xi * sv;
          const float oii = xr * sv + xi * cv;
          if (p < 4) { o0[2 * p] = (_Float16)orr; o0[2 * p + 1] = (_Float16)oii; }
          else       { o1[2 * (p - 4)] = (_Float16)orr; o1[2 * (p - 4) + 1] = (_Float16)oii; }
        }
        *(f16x8*)&Klds[kr * KSTRIDE + kc0]     = o0;
        *(f16x8*)&Klds[kr * KSTRIDE + kc0 + 8] = o1;
      }

      // ---- stage V tile transposed: Vlds[vcol][k], k-blocks (8 halfs) XOR-swizzled ----
      {
        const int vrow = kt * KT + vg * 4;
        const float* vp = xv + (row0 + vrow) * (size_t)(NHEAD * VDIM) + h * VDIM + vc0;
        f16x4 t4[8];
#pragma unroll
        for (int rr = 0; rr < 4; ++rr) {
          float4 v0 = *(const float4*)(vp + (size_t)rr * (NHEAD * VDIM));
          float4 v1 = *(const float4*)(vp + (size_t)rr * (NHEAD * VDIM) + 4);
          t4[0][rr] = (_Float16)v0.x; t4[1][rr] = (_Float16)v0.y;
          t4[2][rr] = (_Float16)v0.z; t4[3][rr] = (_Float16)v0.w;
          t4[4][rr] = (_Float16)v1.x; t4[5][rr] = (_Float16)v1.y;
          t4[6][rr] = (_Float16)v1.z; t4[7][rr] = (_Float16)v1.w;
        }
        const int kblk = vg >> 1;
        const int inb  = (vg & 1) * 4;
#pragma unroll
        for (int ci = 0; ci < 8; ++ci) {
          const int c = vc0 + ci;
          *(f16x4*)&Vlds[c * VSTRIDE + ((kblk ^ vsw) * 8) + inb] = t4[ci];
        }
      }
      __syncthreads();

      // ---- S = Q K^T  (wave: 16 q-rows x 64 k-cols) ----
      f32x4 sfrag[4];
#pragma unroll
      for (int n = 0; n < 4; ++n) sfrag[n] = zf;
#pragma unroll
      for (int n = 0; n < 4; ++n) {
#pragma unroll
        for (int blk = 0; blk < 4; ++blk) {
          f16x8 bfr = *(const f16x8*)&Klds[(n * 16 + l15) * KSTRIDE + blk * 32 + lhi * 8];
          sfrag[n] = __builtin_amdgcn_mfma_f32_16x16x32_f16(qfrag[blk], bfr, sfrag[n], 0, 0, 0);
        }
      }

      // ---- causal mask on diagonal tiles ----
      if (kt >= 2 * qt) {
        const int qg = qt * QT + w * 16 + lhi * 4;  // row of reg 0
#pragma unroll
        for (int n = 0; n < 4; ++n) {
          const int kg = kt * KT + n * 16 + l15;
#pragma unroll
          for (int r = 0; r < 4; ++r)
            if (kg > qg + r) sfrag[n][r] = -1.0e9f;
        }
      }

      // ---- online softmax (row = lhi*4 + r, spread over 16 lanes x 4 frags) ----
      float pvv[4][4];
#pragma unroll
      for (int r = 0; r < 4; ++r) {
        float mx = fmaxf(fmaxf(sfrag[0][r], sfrag[1][r]), fmaxf(sfrag[2][r], sfrag[3][r]));
        mx = fmaxf(mx, __shfl_xor(mx, 1));
        mx = fmaxf(mx, __shfl_xor(mx, 2));
        mx = fmaxf(mx, __shfl_xor(mx, 4));
        mx = fmaxf(mx, __shfl_xor(mx, 8));
        const float Mn = fmaxf(mrun[r], mx);
        const float al = __expf(mrun[r] - Mn);
        mrun[r] = Mn;
        float ls = 0.f;
#pragma unroll
        for (int n = 0; n < 4; ++n) {
          const float p = __expf(sfrag[n][r] - Mn);
          pvv[n][r] = p;
          ls += p;
        }
        ls += __shfl_xor(ls, 1);
        ls += __shfl_xor(ls, 2);
        ls += __shfl_xor(ls, 4);
        ls += __shfl_xor(ls, 8);
        lrun[r] = lrun[r] * al + ls;
#pragma unroll
        for (int i = 0; i < 16; ++i) acc[i][r] *= al;
      }

      // ---- P -> LDS (re-layout D-frag -> A-frag) ----
#pragma unroll
      for (int n = 0; n < 4; ++n)
#pragma unroll
        for (int r = 0; r < 4; ++r)
          Plds[(w * 16 + lhi * 4 + r) * PSTRIDE + n * 16 + l15] = (_Float16)pvv[n][r];
      __syncthreads();   // P writes visible before PV reads

      // ---- O += P V ----
#pragma unroll
      for (int kb = 0; kb < 2; ++kb) {
        f16x8 afr = *(const f16x8*)&Plds[(w * 16 + l15) * PSTRIDE + kb * 32 + lhi * 8];
#pragma unroll
        for (int i = 0; i < 16; ++i) {
          const int vcol = i * 16 + l15;
          f16x8 bfr = *(const f16x8*)&Vlds[vcol * VSTRIDE + (((kb * 4 + lhi) ^ ((vcol >> 3) & 7)) * 8)];
          acc[i] = __builtin_amdgcn_mfma_f32_16x16x32_f16(afr, bfr, acc[i], 0, 0, 0);
        }
      }
    }

    // ---- epilogue: divide by softmax denom, store fp32 ----
    const size_t obase = (row0 + (size_t)qt * QT + w * 16) * (size_t)(NHEAD * VDIM) + h * VDIM;
#pragma unroll
    for (int i = 0; i < 16; ++i) {
#pragma unroll
      for (int r = 0; r < 4; ++r) {
        const int q = lhi * 4 + r;
        out[obase + (size_t)q * (NHEAD * VDIM) + i * 16 + l15] = acc[i][r] / lrun[r];
      }
    }
  }
}

extern "C" void kernel_launch(void* const* d_in, const int* in_sizes, int n_in,
                              void* d_out, int out_size, void* d_ws, size_t ws_size,
                              hipStream_t stream) {
  const float* xq   = (const float*)d_in[0];
  const float* xk   = (const float*)d_in[1];
  const float* xv   = (const float*)d_in[2];
  // d_in[3] = mask (unused: causal mask computed analytically)
  const float* cosT = (const float*)d_in[4];
  const float* sinT = (const float*)d_in[5];
  float* out = (float*)d_out;

  dim3 grid(4, 128);   // balanced q-tile pairs x (chunk*head)
  dim3 block(512);
  attn_fused<<<grid, block, 0, stream>>>(xq, xk, xv, cosT, sinT, out);
}

// Round 5
// 250.730 us; speedup vs baseline: 1.5693x; 1.0210x over previous
//
#include <hip/hip_runtime.h>

// Fused chunked causal attention + RoPE for MI355X (gfx950).
// B=4, SLEN=4096, H=8, ZD=128, VD=256, CHUNK=1024 -> 16 chunks x 8 heads.
// fp32 in/out; fp16 MFMA (16x16x32), fp32 accum.
// Round 5: fix cvt_pkrtz return-type (compile error in r4); logic identical:
// in-block software pipeline (reg-prefetch + double-buffered K/V LDS,
// 2 barriers/tile), pkrtz packed converts, exp2-based deferred-max softmax,
// XCD-grouped block swizzle. 1 block/CU by design.

#define NHEAD 8
#define ZDIM  128
#define VDIM  256
#define CHUNK 1024
#define QT    128   // q rows per q-tile
#define KT    64    // k rows per tile
#define NW    8     // waves per block

typedef _Float16 f16x8 __attribute__((ext_vector_type(8)));
typedef _Float16 f16x4 __attribute__((ext_vector_type(4)));
typedef __fp16   h16x2 __attribute__((ext_vector_type(2)));   // cvt_pkrtz return type
typedef float    f32x4 __attribute__((ext_vector_type(4)));
typedef unsigned int u32;

#define KSTRIDE 136   // halfs per K-lds row (128 + 8 pad)
#define VSTRIDE 72    // halfs per V^T-lds row (64 + 8 pad)
#define PSTRIDE 72    // halfs per P-lds row  (64 + 8 pad)
#define LOG2E   1.44269504088896f
#define RTHR    11.5415603f   /* 8 * LOG2E : defer-max threshold */

__global__ __launch_bounds__(512, 2)
void attn_fused(const float* __restrict__ xq, const float* __restrict__ xk,
                const float* __restrict__ xv, const float* __restrict__ cosT,
                const float* __restrict__ sinT, float* __restrict__ out)
{
  __shared__ _Float16 Klds[2][KT * KSTRIDE];     // 34.8 KB
  __shared__ _Float16 Vlds[2][VDIM * VSTRIDE];   // 73.7 KB  (transposed, k-blk XOR swizzle)
  __shared__ _Float16 Plds[NW * 16 * PSTRIDE];   // 18.4 KB  (per-wave stripes)

  // XCD-grouping swizzle: hw block b -> logical d; blocks round-robin XCDs by b%8,
  // so d = (b&7)*64 + (b>>3) puts 64 consecutive logical blocks (16 ch * 4 qpair)
  // on one XCD -> the 4 qpair-blocks sharing a (chunk,head) K/V stream share L2.
  const int b = (int)blockIdx.x;
  const int d = (b & 7) * 64 + (b >> 3);         // bijective on [0,512)
  const int qpair = d & 3;                       // 0..3 -> q-tiles {7-qpair, qpair}
  const int ch = d >> 2;                         // 0..127
  const int h  = ch & 7;
  const int cb = ch >> 3;

  const int tid  = threadIdx.x;
  const int w    = tid >> 6;
  const int lane = tid & 63;
  const int l15  = lane & 15;
  const int lhi  = lane >> 4;

  const size_t row0 = (size_t)cb * CHUNK;

  // staging thread mapping (loop-invariant)
  const int kr  = tid >> 3;               // K row 0..63
  const int kc0 = (tid & 7) * 16;         // K col group
  const int vg  = tid >> 5;               // 0..15 -> V rows vg*4..+3
  const int vc0 = (tid & 31) * 8;         // V col group
  const int vsw = tid & 7;                // = (c>>3)&7 for c in [vc0,vc0+8)
  const int kblk = vg >> 1;
  const int inb  = (vg & 1) * 4;

  // staging registers (prefetch one tile ahead)
  f32x4 kb0, kb1, kb2, kb3;
  f32x4 vb0, vb1, vb2, vb3, vb4, vb5, vb6, vb7;
  f32x4 ckv0, ckv1, skv0, skv1;

  auto LOADT = [&](int kt1) {
    const int krow = kt1 * KT + kr;
    const float* kp = xk + (row0 + krow) * (size_t)(NHEAD * ZDIM) + h * ZDIM + kc0;
    kb0 = *(const f32x4*)(kp);      kb1 = *(const f32x4*)(kp + 4);
    kb2 = *(const f32x4*)(kp + 8);  kb3 = *(const f32x4*)(kp + 12);
    const float* ck = cosT + krow * (ZDIM / 2) + (kc0 >> 1);
    const float* sk = sinT + krow * (ZDIM / 2) + (kc0 >> 1);
    ckv0 = *(const f32x4*)(ck); ckv1 = *(const f32x4*)(ck + 4);
    skv0 = *(const f32x4*)(sk); skv1 = *(const f32x4*)(sk + 4);
    const int vrow = kt1 * KT + vg * 4;
    const float* vp = xv + (row0 + vrow) * (size_t)(NHEAD * VDIM) + h * VDIM + vc0;
    vb0 = *(const f32x4*)(vp);         vb1 = *(const f32x4*)(vp + 4);
    vb2 = *(const f32x4*)(vp + 2048);  vb3 = *(const f32x4*)(vp + 2052);
    vb4 = *(const f32x4*)(vp + 4096);  vb5 = *(const f32x4*)(vp + 4100);
    vb6 = *(const f32x4*)(vp + 6144);  vb7 = *(const f32x4*)(vp + 6148);
  };

#define KC(j) ((j) < 4 ? kb0[(j)] : (j) < 8 ? kb1[(j)-4] : (j) < 12 ? kb2[(j)-8] : kb3[(j)-12])
#define CF(p) ((p) < 4 ? ckv0[(p)] : ckv1[(p)-4])
#define SF(p) ((p) < 4 ? skv0[(p)] : skv1[(p)-4])
#define VC(r, ci) ((ci) < 4 ? ((r)==0?vb0:(r)==1?vb2:(r)==2?vb4:vb6)[(ci)] \
                            : ((r)==0?vb1:(r)==1?vb3:(r)==2?vb5:vb7)[(ci)-4])

  auto WRITET = [&](int bufi) {
    // K with RoPE -> Klds[bufi], packed converts
    union { h16x2 h2[8]; u32 u[8]; } ko;
#pragma unroll
    for (int p = 0; p < 8; ++p) {
      const float cv = CF(p), sv = SF(p);
      const float xr = KC(2 * p), xi = KC(2 * p + 1);
      const float orr = xr * cv - xi * sv;
      const float oii = xr * sv + xi * cv;
      ko.h2[p] = __builtin_amdgcn_cvt_pkrtz(orr, oii);
    }
    _Float16* kdst = &Klds[bufi][kr * KSTRIDE + kc0];
    ((u32*)kdst)[0] = ko.u[0]; ((u32*)kdst)[1] = ko.u[1];
    ((u32*)kdst)[2] = ko.u[2]; ((u32*)kdst)[3] = ko.u[3];
    ((u32*)kdst)[4] = ko.u[4]; ((u32*)kdst)[5] = ko.u[5];
    ((u32*)kdst)[6] = ko.u[6]; ((u32*)kdst)[7] = ko.u[7];
    // V transposed -> Vlds[bufi]
#pragma unroll
    for (int ci = 0; ci < 8; ++ci) {
      union { h16x2 a[2]; f16x4 v; } t;
      t.a[0] = __builtin_amdgcn_cvt_pkrtz(VC(0, ci), VC(1, ci));
      t.a[1] = __builtin_amdgcn_cvt_pkrtz(VC(2, ci), VC(3, ci));
      *(f16x4*)&Vlds[bufi][(vc0 + ci) * VSTRIDE + ((kblk ^ vsw) * 8) + inb] = t.v;
    }
  };

  for (int half = 0; half < 2; ++half) {
    const int qt = half ? qpair : (7 - qpair);   // heavy q-tile first

    // ---- Q tile -> registers (RoPE'd fp16 A-frags) ----
    const int qrow = qt * QT + w * 16 + l15;
    const float* qp = xq + (row0 + qrow) * (size_t)(NHEAD * ZDIM) + h * ZDIM;
    const float* cq = cosT + qrow * (ZDIM / 2);
    const float* sq = sinT + qrow * (ZDIM / 2);
    f16x8 qfrag[4];
#pragma unroll
    for (int blk = 0; blk < 4; ++blk) {
      const int d0 = blk * 32 + lhi * 8;
      f32x4 a  = *(const f32x4*)(qp + d0);
      f32x4 bb = *(const f32x4*)(qp + d0 + 4);
      union { h16x2 h2[4]; f16x8 v; } fr;
#pragma unroll
      for (int p = 0; p < 4; ++p) {
        const float cv = cq[(d0 >> 1) + p];
        const float sv = sq[(d0 >> 1) + p];
        const float xr = (p < 2 ? a[2 * p] : bb[2 * p - 4]);
        const float xi = (p < 2 ? a[2 * p + 1] : bb[2 * p - 3]);
        fr.h2[p] = __builtin_amdgcn_cvt_pkrtz(xr * cv - xi * sv, xr * sv + xi * cv);
      }
      qfrag[blk] = fr.v;
    }

    const f32x4 zf = {0.f, 0.f, 0.f, 0.f};
    f32x4 acc[16];
#pragma unroll
    for (int i = 0; i < 16; ++i) acc[i] = zf;
    float mrun2[4] = {-1e30f, -1e30f, -1e30f, -1e30f};  // running max, log2 domain
    float lrun[4]  = {0.f, 0.f, 0.f, 0.f};              // per-lane partial denominators

    const int nkt = 2 * qt + 2;

    LOADT(0);   // prologue prefetch
    int buf = 0;

    for (int kt = 0; kt < nkt; ++kt) {
      // ---- convert + write prefetched tile into LDS buf ----
      WRITET(buf);
      if (kt + 1 < nkt) LOADT(kt + 1);   // next tile's loads in flight during compute
      __syncthreads();                   // staging visible

      // ---- S = Q K^T ----
      f32x4 sfrag[4];
#pragma unroll
      for (int n = 0; n < 4; ++n) sfrag[n] = zf;
#pragma unroll
      for (int n = 0; n < 4; ++n) {
#pragma unroll
        for (int blk = 0; blk < 4; ++blk) {
          f16x8 bfr = *(const f16x8*)&Klds[buf][(n * 16 + l15) * KSTRIDE + blk * 32 + lhi * 8];
          sfrag[n] = __builtin_amdgcn_mfma_f32_16x16x32_f16(qfrag[blk], bfr, sfrag[n], 0, 0, 0);
        }
      }

      // ---- causal mask on diagonal tiles ----
      if (kt >= 2 * qt) {
        const int qg = qt * QT + w * 16 + lhi * 4;
#pragma unroll
        for (int n = 0; n < 4; ++n) {
          const int kg = kt * KT + n * 16 + l15;
#pragma unroll
          for (int r = 0; r < 4; ++r)
            if (kg > qg + r) sfrag[n][r] = -1.0e9f;
        }
      }

      // ---- online softmax, deferred-max (THR=8 nats) ----
      float mx2v[4];
      bool need = false;
#pragma unroll
      for (int r = 0; r < 4; ++r) {
        float mx = fmaxf(fmaxf(sfrag[0][r], sfrag[1][r]), fmaxf(sfrag[2][r], sfrag[3][r]));
        mx = fmaxf(mx, __shfl_xor(mx, 1));
        mx = fmaxf(mx, __shfl_xor(mx, 2));
        mx = fmaxf(mx, __shfl_xor(mx, 4));
        mx = fmaxf(mx, __shfl_xor(mx, 8));
        mx2v[r] = mx * LOG2E;
        need = need || (mx2v[r] > mrun2[r] + RTHR);
      }
      if (__any(need)) {
#pragma unroll
        for (int r = 0; r < 4; ++r) {
          const float Mn2 = fmaxf(mrun2[r], mx2v[r]);
          const float al = exp2f(mrun2[r] - Mn2);
          mrun2[r] = Mn2;
          lrun[r] *= al;
#pragma unroll
          for (int i = 0; i < 16; ++i) acc[i][r] *= al;
        }
      }
#pragma unroll
      for (int r = 0; r < 4; ++r) {
#pragma unroll
        for (int n = 0; n < 4; ++n) {
          const float p = exp2f(fmaf(sfrag[n][r], LOG2E, -mrun2[r]));
          lrun[r] += p;   // per-lane partial; reduced in epilogue
          Plds[(w * 16 + lhi * 4 + r) * PSTRIDE + n * 16 + l15] = (_Float16)p;
        }
      }
      __syncthreads();                   // P visible; prior-tile PV reads drained

      // ---- O += P V ----
#pragma unroll
      for (int kb = 0; kb < 2; ++kb) {
        f16x8 afr = *(const f16x8*)&Plds[(w * 16 + l15) * PSTRIDE + kb * 32 + lhi * 8];
#pragma unroll
        for (int i = 0; i < 16; ++i) {
          const int vcol = i * 16 + l15;
          f16x8 bfr = *(const f16x8*)&Vlds[buf][vcol * VSTRIDE + (((kb * 4 + lhi) ^ ((vcol >> 3) & 7)) * 8)];
          acc[i] = __builtin_amdgcn_mfma_f32_16x16x32_f16(afr, bfr, acc[i], 0, 0, 0);
        }
      }
      buf ^= 1;
    }

    // ---- epilogue: reduce denominators, store fp32 ----
    float linv[4];
#pragma unroll
    for (int r = 0; r < 4; ++r) {
      float ls = lrun[r];
      ls += __shfl_xor(ls, 1);
      ls += __shfl_xor(ls, 2);
      ls += __shfl_xor(ls, 4);
      ls += __shfl_xor(ls, 8);
      linv[r] = 1.0f / ls;
    }
    const size_t obase = (row0 + (size_t)qt * QT + w * 16) * (size_t)(NHEAD * VDIM) + h * VDIM;
#pragma unroll
    for (int i = 0; i < 16; ++i) {
#pragma unroll
      for (int r = 0; r < 4; ++r) {
        const int q = lhi * 4 + r;
        out[obase + (size_t)q * (NHEAD * VDIM) + i * 16 + l15] = acc[i][r] * linv[r];
      }
    }
    __syncthreads();   // all PV reads of this half drained before next half restages LDS
  }
}

extern "C" void kernel_launch(void* const* d_in, const int* in_sizes, int n_in,
                              void* d_out, int out_size, void* d_ws, size_t ws_size,
                              hipStream_t stream) {
  const float* xq   = (const float*)d_in[0];
  const float* xk   = (const float*)d_in[1];
  const float* xv   = (const float*)d_in[2];
  // d_in[3] = mask (unused: causal mask computed analytically)
  const float* cosT = (const float*)d_in[4];
  const float* sinT = (const float*)d_in[5];
  float* out = (float*)d_out;

  dim3 grid(512);
  dim3 block(512);
  attn_fused<<<grid, block, 0, stream>>>(xq, xk, xv, cosT, sinT, out);
}

// Round 6
// 228.533 us; speedup vs baseline: 1.7217x; 1.0971x over previous
//
#include <hip/hip_runtime.h>

// Fused chunked causal attention + RoPE for MI355X (gfx950).
// B=4, SLEN=4096, H=8, ZD=128, VD=256, CHUNK=1024 -> 16 chunks x 8 heads.
// fp32 in/out; fp16 MFMA (16x16x32), fp32 accum.
// Round 6: 32 q-rows/wave (QT=256/block) -> halves per-work LDS reads;
// 1 barrier/k-tile (wave-private P, double-buffered K/V); per-wave skip of
// fully-masked diagonal tiles; no reg-prefetch (VGPR budget -> acc).

#define NHEAD 8
#define ZDIM  128
#define VDIM  256
#define CHUNK 1024
#define QTILE 256   // q rows per block
#define KT    64    // k rows per tile
#define NW    8     // waves per block

typedef _Float16 f16x8 __attribute__((ext_vector_type(8)));
typedef _Float16 f16x4 __attribute__((ext_vector_type(4)));
typedef __fp16   h16x2 __attribute__((ext_vector_type(2)));   // cvt_pkrtz return type
typedef float    f32x4 __attribute__((ext_vector_type(4)));
typedef unsigned int u32;

#define KSTRIDE 136   // halfs per K-lds row (128 + 8 pad)
#define VSTRIDE 72    // halfs per V^T-lds row (64 + 8 pad)
#define PSTRIDE 76    // halfs per P-lds row (64 + 12 pad: conflict-free lhi banks)
#define LOG2E   1.44269504088896f
#define RTHR    11.5415603f   /* 8 nats in log2 domain: defer-max threshold */

__global__ __launch_bounds__(512, 2)
void attn_fused(const float* __restrict__ xq, const float* __restrict__ xk,
                const float* __restrict__ xv, const float* __restrict__ cosT,
                const float* __restrict__ sinT, float* __restrict__ out)
{
  __shared__ _Float16 Klds[2][KT * KSTRIDE];     // 34.8 KB
  __shared__ _Float16 Vlds[2][VDIM * VSTRIDE];   // 73.7 KB (transposed, k-blk XOR swizzle)
  __shared__ _Float16 Plds[NW * 32 * PSTRIDE];   // 38.9 KB (wave-private stripes)

  // XCD-grouping swizzle (bijective on [0,256)): consecutive logical blocks
  // (same chunk,head; the 2 qpair blocks) land on one XCD -> shared L2 K/V stream.
  const int b = (int)blockIdx.x;
  const int d = (b & 7) * 32 + (b >> 3);
  const int qpair = d & 1;                       // 0 -> {3,0}, 1 -> {2,1}
  const int ch = d >> 1;                         // 0..127
  const int h  = ch & 7;
  const int cb = ch >> 3;

  const int tid  = threadIdx.x;
  const int w    = tid >> 6;
  const int lane = tid & 63;
  const int l15  = lane & 15;
  const int lhi  = lane >> 4;

  const size_t row0 = (size_t)cb * CHUNK;

  // staging thread mapping (loop-invariant)
  const int kr   = tid >> 3;              // K row 0..63
  const int kc0  = (tid & 7) * 16;        // K col group
  const int vg   = tid >> 5;              // 0..15 -> V rows vg*4..+3
  const int vc0  = (tid & 31) * 8;        // V col group
  const int vsw  = tid & 7;               // = (c>>3)&7 for c in [vc0,vc0+8)
  const int kblk = vg >> 1;
  const int inb  = (vg & 1) * 4;

  int buf = 0;

  for (int half = 0; half < 2; ++half) {
    const int qt = half ? qpair : (3 - qpair);   // heavy q-tile first

    // ---- Q tile -> registers: 2 sub-tiles of 16 rows (RoPE'd fp16 A-frags) ----
    f16x8 qfrag[2][4];
#pragma unroll
    for (int s = 0; s < 2; ++s) {
      const int qrow = qt * QTILE + w * 32 + s * 16 + l15;
      const float* qp = xq + (row0 + qrow) * (size_t)(NHEAD * ZDIM) + h * ZDIM;
      const float* cq = cosT + qrow * (ZDIM / 2);
      const float* sq = sinT + qrow * (ZDIM / 2);
#pragma unroll
      for (int blk = 0; blk < 4; ++blk) {
        const int d0 = blk * 32 + lhi * 8;
        f32x4 a  = *(const f32x4*)(qp + d0);
        f32x4 bb = *(const f32x4*)(qp + d0 + 4);
        union { h16x2 h2[4]; f16x8 v; } fr;
#pragma unroll
        for (int p = 0; p < 4; ++p) {
          const float cv = cq[(d0 >> 1) + p];
          const float sv = sq[(d0 >> 1) + p];
          const float xr = (p < 2 ? a[2 * p] : bb[2 * p - 4]);
          const float xi = (p < 2 ? a[2 * p + 1] : bb[2 * p - 3]);
          fr.h2[p] = __builtin_amdgcn_cvt_pkrtz(xr * cv - xi * sv, xr * sv + xi * cv);
        }
        qfrag[s][blk] = fr.v;
      }
    }

    const f32x4 zf = {0.f, 0.f, 0.f, 0.f};
    f32x4 acc[2][16];
#pragma unroll
    for (int s = 0; s < 2; ++s)
#pragma unroll
      for (int i = 0; i < 16; ++i) acc[s][i] = zf;
    float mrun2[2][4], lrun[2][4];
#pragma unroll
    for (int s = 0; s < 2; ++s)
#pragma unroll
      for (int r = 0; r < 4; ++r) { mrun2[s][r] = -1e30f; lrun[s][r] = 0.f; }

    const int nkt = 4 * (qt + 1);
    const int wq0 = qt * QTILE + w * 32;     // wave's lowest q-row

    for (int kt = 0; kt < nkt; ++kt) {
      // ---- stage K tile with RoPE -> Klds[buf] ----
      {
        const int krow = kt * KT + kr;
        const float* kp = xk + (row0 + krow) * (size_t)(NHEAD * ZDIM) + h * ZDIM + kc0;
        const float* ck = cosT + krow * (ZDIM / 2) + (kc0 >> 1);
        const float* sk = sinT + krow * (ZDIM / 2) + (kc0 >> 1);
        f32x4 k0 = *(const f32x4*)(kp);      f32x4 k1 = *(const f32x4*)(kp + 4);
        f32x4 k2 = *(const f32x4*)(kp + 8);  f32x4 k3 = *(const f32x4*)(kp + 12);
        f32x4 c0 = *(const f32x4*)(ck);      f32x4 c1 = *(const f32x4*)(ck + 4);
        f32x4 s0 = *(const f32x4*)(sk);      f32x4 s1 = *(const f32x4*)(sk + 4);
        union { h16x2 h2[8]; u32 u[8]; } ko;
#pragma unroll
        for (int p = 0; p < 8; ++p) {
          const float cv = (p < 4 ? c0[p] : c1[p - 4]);
          const float sv = (p < 4 ? s0[p] : s1[p - 4]);
          const int j = 2 * p;
          const float xr = (j < 4 ? k0[j] : j < 8 ? k1[j - 4] : j < 12 ? k2[j - 8] : k3[j - 12]);
          const float xi = (j + 1 < 4 ? k0[j + 1] : j + 1 < 8 ? k1[j - 3] : j + 1 < 12 ? k2[j - 7] : k3[j - 11]);
          ko.h2[p] = __builtin_amdgcn_cvt_pkrtz(xr * cv - xi * sv, xr * sv + xi * cv);
        }
        u32* kdst = (u32*)&Klds[buf][kr * KSTRIDE + kc0];
        kdst[0] = ko.u[0]; kdst[1] = ko.u[1]; kdst[2] = ko.u[2]; kdst[3] = ko.u[3];
        kdst[4] = ko.u[4]; kdst[5] = ko.u[5]; kdst[6] = ko.u[6]; kdst[7] = ko.u[7];
      }
      // ---- stage V tile transposed -> Vlds[buf] ----
      {
        const int vrow = kt * KT + vg * 4;
        const float* vp = xv + (row0 + vrow) * (size_t)(NHEAD * VDIM) + h * VDIM + vc0;
        f32x4 v0 = *(const f32x4*)(vp);         f32x4 v1 = *(const f32x4*)(vp + 4);
        f32x4 v2 = *(const f32x4*)(vp + 2048);  f32x4 v3 = *(const f32x4*)(vp + 2052);
        f32x4 v4 = *(const f32x4*)(vp + 4096);  f32x4 v5 = *(const f32x4*)(vp + 4100);
        f32x4 v6 = *(const f32x4*)(vp + 6144);  f32x4 v7 = *(const f32x4*)(vp + 6148);
#pragma unroll
        for (int ci = 0; ci < 8; ++ci) {
          const float e0 = (ci < 4 ? v0[ci] : v1[ci - 4]);
          const float e1 = (ci < 4 ? v2[ci] : v3[ci - 4]);
          const float e2 = (ci < 4 ? v4[ci] : v5[ci - 4]);
          const float e3 = (ci < 4 ? v6[ci] : v7[ci - 4]);
          union { h16x2 a[2]; f16x4 v; } t;
          t.a[0] = __builtin_amdgcn_cvt_pkrtz(e0, e1);
          t.a[1] = __builtin_amdgcn_cvt_pkrtz(e2, e3);
          *(f16x4*)&Vlds[buf][(vc0 + ci) * VSTRIDE + ((kblk ^ vsw) * 8) + inb] = t.v;
        }
      }
      __syncthreads();   // staging visible; also fences prior reads of this buf

      // ---- per-wave skip of fully-masked diagonal tiles ----
      if (kt * KT <= wq0 + 31) {
        // ---- S = Q K^T (two 16-row sub-tiles share K frags) ----
        f32x4 sf[2][4];
#pragma unroll
        for (int s = 0; s < 2; ++s)
#pragma unroll
          for (int n = 0; n < 4; ++n) sf[s][n] = zf;
#pragma unroll
        for (int n = 0; n < 4; ++n) {
#pragma unroll
          for (int blk = 0; blk < 4; ++blk) {
            f16x8 bfr = *(const f16x8*)&Klds[buf][(n * 16 + l15) * KSTRIDE + blk * 32 + lhi * 8];
            sf[0][n] = __builtin_amdgcn_mfma_f32_16x16x32_f16(qfrag[0][blk], bfr, sf[0][n], 0, 0, 0);
            sf[1][n] = __builtin_amdgcn_mfma_f32_16x16x32_f16(qfrag[1][blk], bfr, sf[1][n], 0, 0, 0);
          }
        }

        // ---- causal mask (partial tiles only) ----
        if (kt * KT + 63 > wq0) {
#pragma unroll
          for (int s = 0; s < 2; ++s) {
            const int qg = wq0 + s * 16 + lhi * 4;
#pragma unroll
            for (int n = 0; n < 4; ++n) {
              const int kg = kt * KT + n * 16 + l15;
#pragma unroll
              for (int r = 0; r < 4; ++r)
                if (kg > qg + r) sf[s][n][r] = -1.0e9f;
            }
          }
        }

        // ---- online softmax, deferred-max ----
        float mx2v[2][4];
        bool need = false;
#pragma unroll
        for (int s = 0; s < 2; ++s) {
#pragma unroll
          for (int r = 0; r < 4; ++r) {
            float mx = fmaxf(fmaxf(sf[s][0][r], sf[s][1][r]), fmaxf(sf[s][2][r], sf[s][3][r]));
            mx = fmaxf(mx, __shfl_xor(mx, 1));
            mx = fmaxf(mx, __shfl_xor(mx, 2));
            mx = fmaxf(mx, __shfl_xor(mx, 4));
            mx = fmaxf(mx, __shfl_xor(mx, 8));
            mx2v[s][r] = mx * LOG2E;
            need = need || (mx2v[s][r] > mrun2[s][r] + RTHR);
          }
        }
        if (__any(need)) {
#pragma unroll
          for (int s = 0; s < 2; ++s) {
#pragma unroll
            for (int r = 0; r < 4; ++r) {
              const float Mn2 = fmaxf(mrun2[s][r], mx2v[s][r]);
              const float al = exp2f(mrun2[s][r] - Mn2);
              mrun2[s][r] = Mn2;
              lrun[s][r] *= al;
#pragma unroll
              for (int i = 0; i < 16; ++i) acc[s][i][r] *= al;
            }
          }
        }
#pragma unroll
        for (int s = 0; s < 2; ++s) {
#pragma unroll
          for (int r = 0; r < 4; ++r) {
#pragma unroll
            for (int n = 0; n < 4; ++n) {
              const float p = exp2f(fmaf(sf[s][n][r], LOG2E, -mrun2[s][r]));
              lrun[s][r] += p;   // per-lane partial; reduced in epilogue
              Plds[(w * 32 + s * 16 + lhi * 4 + r) * PSTRIDE + n * 16 + l15] = (_Float16)p;
            }
          }
        }
        // wave-private P: compiler orders ds_write -> ds_read via lgkmcnt (no barrier)

        // ---- O += P V (V frags shared across sub-tiles) ----
#pragma unroll
        for (int kb = 0; kb < 2; ++kb) {
          f16x8 af0 = *(const f16x8*)&Plds[(w * 32 + l15) * PSTRIDE + kb * 32 + lhi * 8];
          f16x8 af1 = *(const f16x8*)&Plds[(w * 32 + 16 + l15) * PSTRIDE + kb * 32 + lhi * 8];
#pragma unroll
          for (int i = 0; i < 16; ++i) {
            const int vcol = i * 16 + l15;
            f16x8 bfr = *(const f16x8*)&Vlds[buf][vcol * VSTRIDE + (((kb * 4 + lhi) ^ ((vcol >> 3) & 7)) * 8)];
            acc[0][i] = __builtin_amdgcn_mfma_f32_16x16x32_f16(af0, bfr, acc[0][i], 0, 0, 0);
            acc[1][i] = __builtin_amdgcn_mfma_f32_16x16x32_f16(af1, bfr, acc[1][i], 0, 0, 0);
          }
        }
      }
      buf ^= 1;
    }

    // ---- epilogue: reduce denominators, store fp32 ----
#pragma unroll
    for (int s = 0; s < 2; ++s) {
      float linv[4];
#pragma unroll
      for (int r = 0; r < 4; ++r) {
        float ls = lrun[s][r];
        ls += __shfl_xor(ls, 1);
        ls += __shfl_xor(ls, 2);
        ls += __shfl_xor(ls, 4);
        ls += __shfl_xor(ls, 8);
        linv[r] = 1.0f / ls;
      }
      const size_t obase = (row0 + (size_t)qt * QTILE + w * 32 + s * 16) * (size_t)(NHEAD * VDIM) + h * VDIM;
#pragma unroll
      for (int i = 0; i < 16; ++i) {
#pragma unroll
        for (int r = 0; r < 4; ++r) {
          const int q = lhi * 4 + r;
          out[obase + (size_t)q * (NHEAD * VDIM) + i * 16 + l15] = acc[s][i][r] * linv[r];
        }
      }
    }
    __syncthreads();   // half boundary safety
  }
}

extern "C" void kernel_launch(void* const* d_in, const int* in_sizes, int n_in,
                              void* d_out, int out_size, void* d_ws, size_t ws_size,
                              hipStream_t stream) {
  const float* xq   = (const float*)d_in[0];
  const float* xk   = (const float*)d_in[1];
  const float* xv   = (const float*)d_in[2];
  // d_in[3] = mask (unused: causal mask computed analytically)
  const float* cosT = (const float*)d_in[4];
  const float* sinT = (const float*)d_in[5];
  float* out = (float*)d_out;

  dim3 grid(256);   // (2 qpairs) x (128 chunk*head), XCD-swizzled
  dim3 block(512);
  attn_fused<<<grid, block, 0, stream>>>(xq, xk, xv, cosT, sinT, out);
}

// Round 7
// 210.820 us; speedup vs baseline: 1.8664x; 1.0840x over previous
//
#include <hip/hip_runtime.h>

// Fused chunked causal attention + RoPE for MI355X (gfx950).
// B=4, SLEN=4096, H=8, ZD=128, VD=256, CHUNK=1024 -> 16 chunks x 8 heads.
// fp32 in/out; fp16 MFMA (16x16x32), fp32 accum.
// Round 7: registers cap us at 2 waves/SIMD (128 arch + 128 acc = 256/wave).
// -> 4-wave blocks (256 thr), QTILE=128, KT=32, LDS 76KB => TWO blocks/CU
// (independent barrier domains, phase-offset overlap). Grid 512 = 2/CU exact.

#define NHEAD 8
#define ZDIM  128
#define VDIM  256
#define CHUNK 1024
#define QTILE 128   // q rows per block
#define KT    32    // k rows per tile
#define NW    4     // waves per block

typedef _Float16 f16x8 __attribute__((ext_vector_type(8)));
typedef _Float16 f16x4 __attribute__((ext_vector_type(4)));
typedef __fp16   h16x2 __attribute__((ext_vector_type(2)));   // cvt_pkrtz return type
typedef float    f32x4 __attribute__((ext_vector_type(4)));
typedef unsigned int u32;

#define KSTRIDE 136   // halfs per K-lds row (128 + 8 pad)
#define VSTRIDE 40    // halfs per V^T-lds row (32 + 8 pad)
#define PSTRIDE 76    // halfs per P-lds row (64 + 12 pad)
#define LOG2E   1.44269504088896f
#define RTHR    11.5415603f   /* 8 nats in log2 domain: defer-max threshold */

__global__ __launch_bounds__(256, 2)
void attn_fused(const float* __restrict__ xq, const float* __restrict__ xk,
                const float* __restrict__ xv, const float* __restrict__ cosT,
                const float* __restrict__ sinT, float* __restrict__ out)
{
  __shared__ _Float16 Klds[2][KT * KSTRIDE];     // 17.4 KB
  __shared__ _Float16 Vlds[2][VDIM * VSTRIDE];   // 41.0 KB (transposed, k-blk XOR swizzle)
  __shared__ _Float16 Plds[NW * 32 * PSTRIDE];   // 19.5 KB (wave-private stripes)
  // total 76.0 KB -> 2 blocks/CU

  // XCD-grouping swizzle (bijective on [0,512)): per XCD, 64 consecutive logical
  // blocks = 16 ch x 4 qpairs -> the 4 blocks sharing a (chunk,head) K/V stream
  // co-run on one XCD's L2.
  const int b = (int)blockIdx.x;
  const int d = (b & 7) * 64 + (b >> 3);
  const int qpair = d & 3;                       // 0..3 -> q-tiles {7-qpair, qpair}
  const int ch = d >> 2;                         // 0..127
  const int h  = ch & 7;
  const int cb = ch >> 3;

  const int tid  = threadIdx.x;
  const int w    = tid >> 6;                     // wave 0..3
  const int lane = tid & 63;
  const int l15  = lane & 15;
  const int lhi  = lane >> 4;

  const size_t row0 = (size_t)cb * CHUNK;

  // staging thread mapping (256 threads cover 32x128 K and 32x256 V)
  const int kr   = tid >> 3;              // K row 0..31
  const int kc0  = (tid & 7) * 16;        // K col group
  const int vg   = tid >> 5;              // 0..7 -> V rows vg*4..+3
  const int vc0  = (tid & 31) * 8;        // V col group
  const int vsw  = tid & 3;               // = (c>>3)&3 for c in [vc0,vc0+8)
  const int kblk = vg >> 1;               // k-block 0..3 (8 halfs each)
  const int inb  = (vg & 1) * 4;

  int buf = 0;

  for (int half = 0; half < 2; ++half) {
    const int qt = half ? qpair : (7 - qpair);   // heavy q-tile first

    // ---- Q tile -> registers: 2 sub-tiles of 16 rows (RoPE'd fp16 A-frags) ----
    f16x8 qfrag[2][4];
#pragma unroll
    for (int s = 0; s < 2; ++s) {
      const int qrow = qt * QTILE + w * 32 + s * 16 + l15;
      const float* qp = xq + (row0 + qrow) * (size_t)(NHEAD * ZDIM) + h * ZDIM;
      const float* cq = cosT + qrow * (ZDIM / 2);
      const float* sq = sinT + qrow * (ZDIM / 2);
#pragma unroll
      for (int blk = 0; blk < 4; ++blk) {
        const int d0 = blk * 32 + lhi * 8;
        f32x4 a  = *(const f32x4*)(qp + d0);
        f32x4 bb = *(const f32x4*)(qp + d0 + 4);
        union { h16x2 h2[4]; f16x8 v; } fr;
#pragma unroll
        for (int p = 0; p < 4; ++p) {
          const float cv = cq[(d0 >> 1) + p];
          const float sv = sq[(d0 >> 1) + p];
          const float xr = (p < 2 ? a[2 * p] : bb[2 * p - 4]);
          const float xi = (p < 2 ? a[2 * p + 1] : bb[2 * p - 3]);
          fr.h2[p] = __builtin_amdgcn_cvt_pkrtz(xr * cv - xi * sv, xr * sv + xi * cv);
        }
        qfrag[s][blk] = fr.v;
      }
    }

    const f32x4 zf = {0.f, 0.f, 0.f, 0.f};
    f32x4 acc[2][16];
#pragma unroll
    for (int s = 0; s < 2; ++s)
#pragma unroll
      for (int i = 0; i < 16; ++i) acc[s][i] = zf;
    float mrun2[2][4], lrun[2][4];
#pragma unroll
    for (int s = 0; s < 2; ++s)
#pragma unroll
      for (int r = 0; r < 4; ++r) { mrun2[s][r] = -1e30f; lrun[s][r] = 0.f; }

    const int nkt = 4 * (qt + 1);            // k-tiles of 32 rows
    const int wq0 = qt * QTILE + w * 32;     // wave's lowest q-row

    for (int kt = 0; kt < nkt; ++kt) {
      const int ktb = kt * KT;
      // ---- stage K tile with RoPE -> Klds[buf] ----
      {
        const int krow = ktb + kr;
        const float* kp = xk + (row0 + krow) * (size_t)(NHEAD * ZDIM) + h * ZDIM + kc0;
        const float* ck = cosT + krow * (ZDIM / 2) + (kc0 >> 1);
        const float* sk = sinT + krow * (ZDIM / 2) + (kc0 >> 1);
        f32x4 k0 = *(const f32x4*)(kp);      f32x4 k1 = *(const f32x4*)(kp + 4);
        f32x4 k2 = *(const f32x4*)(kp + 8);  f32x4 k3 = *(const f32x4*)(kp + 12);
        f32x4 c0 = *(const f32x4*)(ck);      f32x4 c1 = *(const f32x4*)(ck + 4);
        f32x4 s0 = *(const f32x4*)(sk);      f32x4 s1 = *(const f32x4*)(sk + 4);
        union { h16x2 h2[8]; u32 u[8]; } ko;
#pragma unroll
        for (int p = 0; p < 8; ++p) {
          const float cv = (p < 4 ? c0[p] : c1[p - 4]);
          const float sv = (p < 4 ? s0[p] : s1[p - 4]);
          const int j = 2 * p;
          const float xr = (j < 4 ? k0[j] : j < 8 ? k1[j - 4] : j < 12 ? k2[j - 8] : k3[j - 12]);
          const float xi = (j + 1 < 4 ? k0[j + 1] : j + 1 < 8 ? k1[j - 3] : j + 1 < 12 ? k2[j - 7] : k3[j - 11]);
          ko.h2[p] = __builtin_amdgcn_cvt_pkrtz(xr * cv - xi * sv, xr * sv + xi * cv);
        }
        u32* kdst = (u32*)&Klds[buf][kr * KSTRIDE + kc0];
        kdst[0] = ko.u[0]; kdst[1] = ko.u[1]; kdst[2] = ko.u[2]; kdst[3] = ko.u[3];
        kdst[4] = ko.u[4]; kdst[5] = ko.u[5]; kdst[6] = ko.u[6]; kdst[7] = ko.u[7];
      }
      // ---- stage V tile transposed -> Vlds[buf] ----
      {
        const int vrow = ktb + vg * 4;
        const float* vp = xv + (row0 + vrow) * (size_t)(NHEAD * VDIM) + h * VDIM + vc0;
        f32x4 v0 = *(const f32x4*)(vp);         f32x4 v1 = *(const f32x4*)(vp + 4);
        f32x4 v2 = *(const f32x4*)(vp + 2048);  f32x4 v3 = *(const f32x4*)(vp + 2052);
        f32x4 v4 = *(const f32x4*)(vp + 4096);  f32x4 v5 = *(const f32x4*)(vp + 4100);
        f32x4 v6 = *(const f32x4*)(vp + 6144);  f32x4 v7 = *(const f32x4*)(vp + 6148);
#pragma unroll
        for (int ci = 0; ci < 8; ++ci) {
          const float e0 = (ci < 4 ? v0[ci] : v1[ci - 4]);
          const float e1 = (ci < 4 ? v2[ci] : v3[ci - 4]);
          const float e2 = (ci < 4 ? v4[ci] : v5[ci - 4]);
          const float e3 = (ci < 4 ? v6[ci] : v7[ci - 4]);
          union { h16x2 a[2]; f16x4 v; } t;
          t.a[0] = __builtin_amdgcn_cvt_pkrtz(e0, e1);
          t.a[1] = __builtin_amdgcn_cvt_pkrtz(e2, e3);
          *(f16x4*)&Vlds[buf][(vc0 + ci) * VSTRIDE + ((kblk ^ vsw) * 8) + inb] = t.v;
        }
      }
      __syncthreads();   // staging visible; single barrier/tile (dbuf proof as r6)

      // ---- per-wave skip of fully-masked tiles ----
      if (ktb <= wq0 + 31) {
        // ---- S = Q K^T (two 16-row sub-tiles share K frags) ----
        f32x4 sf[2][2];
#pragma unroll
        for (int s = 0; s < 2; ++s)
#pragma unroll
          for (int n = 0; n < 2; ++n) sf[s][n] = zf;
#pragma unroll
        for (int n = 0; n < 2; ++n) {
#pragma unroll
          for (int blk = 0; blk < 4; ++blk) {
            f16x8 bfr = *(const f16x8*)&Klds[buf][(n * 16 + l15) * KSTRIDE + blk * 32 + lhi * 8];
            sf[0][n] = __builtin_amdgcn_mfma_f32_16x16x32_f16(qfrag[0][blk], bfr, sf[0][n], 0, 0, 0);
            sf[1][n] = __builtin_amdgcn_mfma_f32_16x16x32_f16(qfrag[1][blk], bfr, sf[1][n], 0, 0, 0);
          }
        }

        // ---- causal mask (partial tiles only) ----
        if (ktb + 31 > wq0) {
#pragma unroll
          for (int s = 0; s < 2; ++s) {
            const int qg = wq0 + s * 16 + lhi * 4;
#pragma unroll
            for (int n = 0; n < 2; ++n) {
              const int kg = ktb + n * 16 + l15;
#pragma unroll
              for (int r = 0; r < 4; ++r)
                if (kg > qg + r) sf[s][n][r] = -1.0e9f;
            }
          }
        }

        // ---- online softmax, deferred-max ----
        float mx2v[2][4];
        bool need = false;
#pragma unroll
        for (int s = 0; s < 2; ++s) {
#pragma unroll
          for (int r = 0; r < 4; ++r) {
            float mx = fmaxf(sf[s][0][r], sf[s][1][r]);
            mx = fmaxf(mx, __shfl_xor(mx, 1));
            mx = fmaxf(mx, __shfl_xor(mx, 2));
            mx = fmaxf(mx, __shfl_xor(mx, 4));
            mx = fmaxf(mx, __shfl_xor(mx, 8));
            mx2v[s][r] = mx * LOG2E;
            need = need || (mx2v[s][r] > mrun2[s][r] + RTHR);
          }
        }
        if (__any(need)) {
#pragma unroll
          for (int s = 0; s < 2; ++s) {
#pragma unroll
            for (int r = 0; r < 4; ++r) {
              const float Mn2 = fmaxf(mrun2[s][r], mx2v[s][r]);
              const float al = exp2f(mrun2[s][r] - Mn2);
              mrun2[s][r] = Mn2;
              lrun[s][r] *= al;
#pragma unroll
              for (int i = 0; i < 16; ++i) acc[s][i][r] *= al;
            }
          }
        }
#pragma unroll
        for (int s = 0; s < 2; ++s) {
#pragma unroll
          for (int r = 0; r < 4; ++r) {
#pragma unroll
            for (int n = 0; n < 2; ++n) {
              const float p = exp2f(fmaf(sf[s][n][r], LOG2E, -mrun2[s][r]));
              lrun[s][r] += p;   // per-lane partial; reduced in epilogue
              Plds[(w * 32 + s * 16 + lhi * 4 + r) * PSTRIDE + n * 16 + l15] = (_Float16)p;
            }
          }
        }
        // wave-private P: ds_write -> ds_read ordered by lgkmcnt within wave

        // ---- O += P V (single 32-k block) ----
        f16x8 af0 = *(const f16x8*)&Plds[(w * 32 + l15) * PSTRIDE + lhi * 8];
        f16x8 af1 = *(const f16x8*)&Plds[(w * 32 + 16 + l15) * PSTRIDE + lhi * 8];
#pragma unroll
        for (int i = 0; i < 16; ++i) {
          const int vcol = i * 16 + l15;
          f16x8 bfr = *(const f16x8*)&Vlds[buf][vcol * VSTRIDE + ((lhi ^ ((vcol >> 3) & 3)) * 8)];
          acc[0][i] = __builtin_amdgcn_mfma_f32_16x16x32_f16(af0, bfr, acc[0][i], 0, 0, 0);
          acc[1][i] = __builtin_amdgcn_mfma_f32_16x16x32_f16(af1, bfr, acc[1][i], 0, 0, 0);
        }
      }
      buf ^= 1;
    }

    // ---- epilogue: reduce denominators, store fp32 ----
#pragma unroll
    for (int s = 0; s < 2; ++s) {
      float linv[4];
#pragma unroll
      for (int r = 0; r < 4; ++r) {
        float ls = lrun[s][r];
        ls += __shfl_xor(ls, 1);
        ls += __shfl_xor(ls, 2);
        ls += __shfl_xor(ls, 4);
        ls += __shfl_xor(ls, 8);
        linv[r] = 1.0f / ls;
      }
      const size_t obase = (row0 + (size_t)qt * QTILE + w * 32 + s * 16) * (size_t)(NHEAD * VDIM) + h * VDIM;
#pragma unroll
      for (int i = 0; i < 16; ++i) {
#pragma unroll
        for (int r = 0; r < 4; ++r) {
          const int q = lhi * 4 + r;
          out[obase + (size_t)q * (NHEAD * VDIM) + i * 16 + l15] = acc[s][i][r] * linv[r];
        }
      }
    }
    __syncthreads();   // half boundary safety
  }
}

extern "C" void kernel_launch(void* const* d_in, const int* in_sizes, int n_in,
                              void* d_out, int out_size, void* d_ws, size_t ws_size,
                              hipStream_t stream) {
  const float* xq   = (const float*)d_in[0];
  const float* xk   = (const float*)d_in[1];
  const float* xv   = (const float*)d_in[2];
  // d_in[3] = mask (unused: causal mask computed analytically)
  const float* cosT = (const float*)d_in[4];
  const float* sinT = (const float*)d_in[5];
  float* out = (float*)d_out;

  dim3 grid(512);    // (4 qpairs) x (128 chunk*head), XCD-swizzled, 2 blocks/CU
  dim3 block(256);   // 4 waves
  attn_fused<<<grid, block, 0, stream>>>(xq, xk, xv, cosT, sinT, out);
}

// Round 8
// 192.003 us; speedup vs baseline: 2.0493x; 1.0980x over previous
//
#include <hip/hip_runtime.h>

// Fused chunked causal attention + RoPE for MI355X (gfx950).
// B=4, SLEN=4096, H=8, ZD=128, VD=256, CHUNK=1024 -> 16 chunks x 8 heads.
// fp32 in/out; fp16 MFMA 32x32x16, fp32 accum.
// Round 8: swapped-operand QK^T (S^T = mfma(K,Q)) -> softmax reduction is
// lane-local (1 shuffle); P packed to fp16 A-frags in registers (cvt_pkrtz +
// shfl_xor(32)) -> no P LDS roundtrip; K chunk-XOR swizzle; V^T stride 36;
// s_setprio around MFMA; Q pre-scaled by log2e. 2 blocks/CU phase-offset.

#define NHEAD 8
#define ZDIM  128
#define VDIM  256
#define CHUNK 1024
#define QTILE 128   // q rows per block (4 waves x 32 rows)
#define KT    32    // k rows per tile
#define NW    4

typedef _Float16 f16x8 __attribute__((ext_vector_type(8)));
typedef _Float16 f16x4 __attribute__((ext_vector_type(4)));
typedef __fp16   h16x2 __attribute__((ext_vector_type(2)));   // cvt_pkrtz return type
typedef float    f32x4  __attribute__((ext_vector_type(4)));
typedef float    f32x16 __attribute__((ext_vector_type(16)));
typedef unsigned int u32;

#define KSTRIDE 136   // halfs per K-lds row (16B-aligned rows; chunk-XOR swizzle)
#define VSTRIDE 36    // halfs per V^T-lds row (32 + 4 pad; b64 reads)
#define LOG2E   1.44269504088896f
#define RTHR    11.5415603f   /* 8 nats in log2 domain: defer-max threshold */

__global__ __launch_bounds__(256, 2)
void attn_fused(const float* __restrict__ xq, const float* __restrict__ xk,
                const float* __restrict__ xv, const float* __restrict__ cosT,
                const float* __restrict__ sinT, float* __restrict__ out)
{
  __shared__ _Float16 Klds[2][KT * KSTRIDE];     // 17.4 KB
  __shared__ _Float16 Vlds[2][VDIM * VSTRIDE];   // 36.9 KB (transposed, k-blk XOR)
  // total 54.3 KB -> 2 blocks/CU

  // XCD-grouping swizzle (bijective on [0,512))
  const int b = (int)blockIdx.x;
  const int d = (b & 7) * 64 + (b >> 3);
  const int qpair = d & 3;                       // 0..3 -> q-tiles {7-qpair, qpair}
  const int ch = d >> 2;                         // 0..127
  const int h  = ch & 7;
  const int cb = ch >> 3;

  const int tid  = threadIdx.x;
  const int w    = tid >> 6;                     // wave 0..3
  const int lane = tid & 63;
  const int l31  = lane & 31;
  const int hi   = lane >> 5;                    // 0/1
  const int vswz = (l31 >> 3) & 3;               // V read XOR
  const int kswz = lane & 15;                    // K read XOR (row&15)

  const size_t row0 = (size_t)cb * CHUNK;

  // staging thread mapping
  const int kr   = tid >> 3;              // K row 0..31
  const int kc0  = (tid & 7) * 16;        // K col group (16 halfs = 2 chunks)
  const int kch0 = (tid & 7) * 2;         // first chunk idx
  const int vg   = tid >> 5;              // 0..7 -> V rows vg*4..+3
  const int vc0  = (tid & 31) * 8;        // V col group
  const int vsw  = tid & 3;               // write-side k-blk XOR
  const int kblk = vg >> 1;
  const int inb  = (vg & 1) * 4;

  int buf = 0;

  for (int half = 0; half < 2; ++half) {
    const int qt = half ? qpair : (7 - qpair);   // heavy q-tile first
    const int wq0 = qt * QTILE + w * 32;         // wave's lowest q-row
    const int qg  = wq0 + l31;                   // this lane's q-row (softmax owner)

    // ---- Q -> registers as 32x32x16 B-frags: lane holds Q[q=l31][d=dblk*16+hi*8+j]*log2e ----
    f16x8 qfrag[8];
    {
      const float* qp = xq + (row0 + qg) * (size_t)(NHEAD * ZDIM) + h * ZDIM;
      const float* cq = cosT + qg * (ZDIM / 2);
      const float* sq = sinT + qg * (ZDIM / 2);
#pragma unroll
      for (int dblk = 0; dblk < 8; ++dblk) {
        const int d0 = dblk * 16 + hi * 8;
        f32x4 a  = *(const f32x4*)(qp + d0);
        f32x4 b2 = *(const f32x4*)(qp + d0 + 4);
        f32x4 cv = *(const f32x4*)(cq + (d0 >> 1));
        f32x4 sv = *(const f32x4*)(sq + (d0 >> 1));
        union { h16x2 h2[4]; f16x8 v; } fr;
#pragma unroll
        for (int p = 0; p < 4; ++p) {
          const float xr = (p < 2 ? a[2 * p] : b2[2 * p - 4]);
          const float xi = (p < 2 ? a[2 * p + 1] : b2[2 * p - 3]);
          fr.h2[p] = __builtin_amdgcn_cvt_pkrtz((xr * cv[p] - xi * sv[p]) * LOG2E,
                                                (xr * sv[p] + xi * cv[p]) * LOG2E);
        }
        qfrag[dblk] = fr.v;
      }
    }

    const f32x16 zf = {};
    f32x16 acc[8];                                // O^T: col=vcol(l31), rows=q
#pragma unroll
    for (int g = 0; g < 8; ++g) acc[g] = zf;
    float mrun = -1e30f;                          // per-lane (its q), log2 domain
    float lrun = 0.f;                             // per-lane partial denominator

    const int nkt = 4 * (qt + 1);

    for (int kt = 0; kt < nkt; ++kt) {
      const int ktb = kt * KT;
      // ---- stage K tile with RoPE -> Klds[buf], chunk-XOR swizzled ----
      {
        const int krow = ktb + kr;
        const float* kp = xk + (row0 + krow) * (size_t)(NHEAD * ZDIM) + h * ZDIM + kc0;
        const float* ck = cosT + krow * (ZDIM / 2) + (kc0 >> 1);
        const float* sk = sinT + krow * (ZDIM / 2) + (kc0 >> 1);
        f32x4 k0 = *(const f32x4*)(kp);      f32x4 k1 = *(const f32x4*)(kp + 4);
        f32x4 k2 = *(const f32x4*)(kp + 8);  f32x4 k3 = *(const f32x4*)(kp + 12);
        f32x4 c0 = *(const f32x4*)(ck);      f32x4 c1 = *(const f32x4*)(ck + 4);
        f32x4 s0 = *(const f32x4*)(sk);      f32x4 s1 = *(const f32x4*)(sk + 4);
        union { h16x2 h2[8]; u32 u[8]; } ko;
#pragma unroll
        for (int p = 0; p < 8; ++p) {
          const float cv = (p < 4 ? c0[p] : c1[p - 4]);
          const float sv = (p < 4 ? s0[p] : s1[p - 4]);
          const int j = 2 * p;
          const float xr = (j < 4 ? k0[j] : j < 8 ? k1[j - 4] : j < 12 ? k2[j - 8] : k3[j - 12]);
          const float xi = (j + 1 < 4 ? k0[j + 1] : j + 1 < 8 ? k1[j - 3] : j + 1 < 12 ? k2[j - 7] : k3[j - 11]);
          ko.h2[p] = __builtin_amdgcn_cvt_pkrtz(xr * cv - xi * sv, xr * sv + xi * cv);
        }
        const int sw = kr & 15;
        u32* p1 = (u32*)&Klds[buf][kr * KSTRIDE + ((kch0 ^ sw) * 8)];
        p1[0] = ko.u[0]; p1[1] = ko.u[1]; p1[2] = ko.u[2]; p1[3] = ko.u[3];
        u32* p2 = (u32*)&Klds[buf][kr * KSTRIDE + (((kch0 + 1) ^ sw) * 8)];
        p2[0] = ko.u[4]; p2[1] = ko.u[5]; p2[2] = ko.u[6]; p2[3] = ko.u[7];
      }
      // ---- stage V tile transposed -> Vlds[buf] ----
      {
        const int vrow = ktb + vg * 4;
        const float* vp = xv + (row0 + vrow) * (size_t)(NHEAD * VDIM) + h * VDIM + vc0;
        f32x4 v0 = *(const f32x4*)(vp);         f32x4 v1 = *(const f32x4*)(vp + 4);
        f32x4 v2 = *(const f32x4*)(vp + 2048);  f32x4 v3 = *(const f32x4*)(vp + 2052);
        f32x4 v4 = *(const f32x4*)(vp + 4096);  f32x4 v5 = *(const f32x4*)(vp + 4100);
        f32x4 v6 = *(const f32x4*)(vp + 6144);  f32x4 v7 = *(const f32x4*)(vp + 6148);
#pragma unroll
        for (int ci = 0; ci < 8; ++ci) {
          const float e0 = (ci < 4 ? v0[ci] : v1[ci - 4]);
          const float e1 = (ci < 4 ? v2[ci] : v3[ci - 4]);
          const float e2 = (ci < 4 ? v4[ci] : v5[ci - 4]);
          const float e3 = (ci < 4 ? v6[ci] : v7[ci - 4]);
          union { h16x2 a2[2]; f16x4 v; } t;
          t.a2[0] = __builtin_amdgcn_cvt_pkrtz(e0, e1);
          t.a2[1] = __builtin_amdgcn_cvt_pkrtz(e2, e3);
          *(f16x4*)&Vlds[buf][(vc0 + ci) * VSTRIDE + ((kblk ^ vsw) * 8) + inb] = t.v;
        }
      }
      __syncthreads();   // staging visible; dbuf makes one barrier/tile safe

      // ---- per-wave skip of fully-masked tiles ----
      if (ktb <= wq0 + 31) {
        // ---- S^T = K Q : D[k][q], col=l31=q, row=k-local ----
        f32x16 s = {};
        __builtin_amdgcn_s_setprio(1);
#pragma unroll
        for (int dblk = 0; dblk < 8; ++dblk) {
          f16x8 kf = *(const f16x8*)&Klds[buf][l31 * KSTRIDE + (((dblk * 2 + hi) ^ kswz) * 8)];
          s = __builtin_amdgcn_mfma_f32_32x32x16_f16(kf, qfrag[dblk], s, 0, 0, 0);
        }
        __builtin_amdgcn_s_setprio(0);

        // ---- causal mask (partial tiles only); k_local = (r&3)+8*(r>>2)+4*hi ----
        if (ktb + 31 > wq0) {
#pragma unroll
          for (int r = 0; r < 16; ++r) {
            const int kg = ktb + ((r & 3) + 8 * (r >> 2) + 4 * hi);
            if (kg > qg) s[r] = -1.0e9f;
          }
        }

        // ---- softmax: lane-local max (15 fmax) + one cross-half shuffle ----
        float m = s[0];
#pragma unroll
        for (int r = 1; r < 16; ++r) m = fmaxf(m, s[r]);
        m = fmaxf(m, __shfl_xor(m, 32));
        const bool need = (m > mrun + RTHR);
        if (__any(need)) {
          const float Mn = fmaxf(mrun, m);
          const float al = exp2f(mrun - Mn);
          mrun = Mn;
          lrun *= al;
#pragma unroll
          for (int r = 0; r < 16; ++r) {
            const float alr = __shfl(al, (r & 3) + 8 * (r >> 2) + 4 * hi);
#pragma unroll
            for (int g = 0; g < 8; ++g) acc[g][r] *= alr;
          }
        }
        float pr[16];
        float lsum = 0.f;
#pragma unroll
        for (int r = 0; r < 16; ++r) {
          pr[r] = exp2f(s[r] - mrun);
          lsum += pr[r];
        }
        lrun += lsum;

        // ---- P -> fp16 A-frags in registers (cvt_pk + shfl_xor(32)), then PV ----
#pragma unroll
        for (int kb = 0; kb < 2; ++kb) {
          union { h16x2 h; u32 u; } A_, B_, C_, D_;
          A_.h = __builtin_amdgcn_cvt_pkrtz(pr[8 * kb + 0], pr[8 * kb + 1]);
          B_.h = __builtin_amdgcn_cvt_pkrtz(pr[8 * kb + 2], pr[8 * kb + 3]);
          C_.h = __builtin_amdgcn_cvt_pkrtz(pr[8 * kb + 4], pr[8 * kb + 5]);
          D_.h = __builtin_amdgcn_cvt_pkrtz(pr[8 * kb + 6], pr[8 * kb + 7]);
          const u32 G1 = hi ? A_.u : C_.u;
          const u32 G2 = hi ? B_.u : D_.u;
          const u32 G1s = (u32)__shfl_xor((int)G1, 32);
          const u32 G2s = (u32)__shfl_xor((int)G2, 32);
          union { u32 u[4]; f16x8 v; } af;
          af.u[0] = hi ? G1s : A_.u;
          af.u[1] = hi ? G2s : B_.u;
          af.u[2] = hi ? C_.u : G1s;
          af.u[3] = hi ? D_.u : G2s;
          __builtin_amdgcn_s_setprio(1);
#pragma unroll
          for (int g = 0; g < 8; ++g) {
            const int vcol = g * 32 + l31;
            const int ck = (((kb * 2 + hi) ^ vswz) * 8);
            union { f16x4 h4[2]; f16x8 v; } bf;
            bf.h4[0] = *(const f16x4*)&Vlds[buf][vcol * VSTRIDE + ck];
            bf.h4[1] = *(const f16x4*)&Vlds[buf][vcol * VSTRIDE + ck + 4];
            acc[g] = __builtin_amdgcn_mfma_f32_32x32x16_f16(af.v, bf.v, acc[g], 0, 0, 0);
          }
          __builtin_amdgcn_s_setprio(0);
        }
      }
      buf ^= 1;
    }

    // ---- epilogue: denom reduce (1 shuffle), per-row linv broadcast, store ----
    const float ls = lrun + __shfl_xor(lrun, 32);
    const float linv = 1.0f / ls;
#pragma unroll
    for (int r = 0; r < 16; ++r) {
      const int qloc = (r & 3) + 8 * (r >> 2) + 4 * hi;
      const float lr = __shfl(linv, qloc);
      const size_t ob = (row0 + wq0 + qloc) * (size_t)(NHEAD * VDIM) + h * VDIM + l31;
#pragma unroll
      for (int g = 0; g < 8; ++g)
        out[ob + g * 32] = acc[g][r] * lr;
    }
    __syncthreads();   // half boundary safety
  }
}

extern "C" void kernel_launch(void* const* d_in, const int* in_sizes, int n_in,
                              void* d_out, int out_size, void* d_ws, size_t ws_size,
                              hipStream_t stream) {
  const float* xq   = (const float*)d_in[0];
  const float* xk   = (const float*)d_in[1];
  const float* xv   = (const float*)d_in[2];
  // d_in[3] = mask (unused: causal mask computed analytically)
  const float* cosT = (const float*)d_in[4];
  const float* sinT = (const float*)d_in[5];
  float* out = (float*)d_out;

  dim3 grid(512);    // (4 qpairs) x (128 chunk*head), XCD-swizzled, 2 blocks/CU
  dim3 block(256);   // 4 waves
  attn_fused<<<grid, block, 0, stream>>>(xq, xk, xv, cosT, sinT, out);
}

// Round 9
// 181.999 us; speedup vs baseline: 2.1619x; 1.0550x over previous
//
#include <hip/hip_runtime.h>

// Fused chunked causal attention + RoPE for MI355X (gfx950).
// B=4, SLEN=4096, H=8, ZD=128, VD=256, CHUNK=1024 -> 16 chunks x 8 heads.
// fp32 in/out; fp16 MFMA 32x32x16, fp32 accum.
// Round 9: conflict-free LDS banking. K: 256B rows + chunk^(row&7) swizzle,
// writes cover slot-permutations per phase. V: sub-slot XOR by (vcol>>5)&1
// kills the lane/lane+4 write collision; reads swap halves per (g&1).
// Structure from r8: swapped-operand QK^T, in-register P, defer-max softmax,
// XCD-grouped swizzle, 2 blocks/CU phase-offset.

#define NHEAD 8
#define ZDIM  128
#define VDIM  256
#define CHUNK 1024
#define QTILE 128   // q rows per block (4 waves x 32 rows)
#define KT    32    // k rows per tile
#define NW    4

typedef _Float16 f16x8 __attribute__((ext_vector_type(8)));
typedef _Float16 f16x4 __attribute__((ext_vector_type(4)));
typedef __fp16   h16x2 __attribute__((ext_vector_type(2)));   // cvt_pkrtz return type
typedef float    f32x4  __attribute__((ext_vector_type(4)));
typedef float    f32x16 __attribute__((ext_vector_type(16)));
typedef unsigned int u32;

#define KSTRIDE 128   // halfs per K-lds row (256B == 0 mod 32 banks; XOR-swizzled chunks)
#define VSTRIDE 36    // halfs per V^T-lds row (32 + 4 pad)
#define LOG2E   1.44269504088896f
#define RTHR    11.5415603f   /* 8 nats in log2 domain: defer-max threshold */

__global__ __launch_bounds__(256, 2)
void attn_fused(const float* __restrict__ xq, const float* __restrict__ xk,
                const float* __restrict__ xv, const float* __restrict__ cosT,
                const float* __restrict__ sinT, float* __restrict__ out)
{
  __shared__ _Float16 Klds[2][KT * KSTRIDE];     // 16.0 KB
  __shared__ _Float16 Vlds[2][VDIM * VSTRIDE];   // 36.9 KB (transposed, swizzled)
  // total 52.9 KB -> 2 blocks/CU

  // XCD-grouping swizzle (bijective on [0,512))
  const int b = (int)blockIdx.x;
  const int d = (b & 7) * 64 + (b >> 3);
  const int qpair = d & 3;                       // 0..3 -> q-tiles {7-qpair, qpair}
  const int ch = d >> 2;                         // 0..127
  const int h  = ch & 7;
  const int cb = ch >> 3;

  const int tid  = threadIdx.x;
  const int w    = tid >> 6;                     // wave 0..3
  const int lane = tid & 63;
  const int l31  = lane & 31;
  const int hi   = lane >> 5;                    // 0/1
  const int vswz = (l31 >> 3) & 3;               // V read kblk XOR
  const int kswz = l31 & 7;                      // K read chunk XOR (row&7)

  const size_t row0 = (size_t)cb * CHUNK;

  // staging thread mapping
  const int kr    = tid >> 3;             // K row 0..31
  const int kt8   = tid & 7;              // K chunk pair {kt8, kt8+8}
  const int vg    = tid >> 5;             // 0..7 -> V rows vg*4..+3
  const int vc0   = (tid & 31) * 8;       // V col group
  const int vsw   = tid & 3;              // V write kblk XOR ((vcol>>3)&3)
  const int vflip = ((tid >> 2) & 1) * 4; // V write sub-slot XOR ((vcol>>5)&1)*4
  const int kblk  = vg >> 1;
  const int inb   = (vg & 1) * 4;

  int buf = 0;

  for (int half = 0; half < 2; ++half) {
    const int qt = half ? qpair : (7 - qpair);   // heavy q-tile first
    const int wq0 = qt * QTILE + w * 32;         // wave's lowest q-row
    const int qg  = wq0 + l31;                   // this lane's q-row (softmax owner)

    // ---- Q -> registers as 32x32x16 B-frags (RoPE'd, pre-scaled by log2e) ----
    f16x8 qfrag[8];
    {
      const float* qp = xq + (row0 + qg) * (size_t)(NHEAD * ZDIM) + h * ZDIM;
      const float* cq = cosT + qg * (ZDIM / 2);
      const float* sq = sinT + qg * (ZDIM / 2);
#pragma unroll
      for (int dblk = 0; dblk < 8; ++dblk) {
        const int d0 = dblk * 16 + hi * 8;
        f32x4 a  = *(const f32x4*)(qp + d0);
        f32x4 b2 = *(const f32x4*)(qp + d0 + 4);
        f32x4 cv = *(const f32x4*)(cq + (d0 >> 1));
        f32x4 sv = *(const f32x4*)(sq + (d0 >> 1));
        union { h16x2 h2[4]; f16x8 v; } fr;
#pragma unroll
        for (int p = 0; p < 4; ++p) {
          const float xr = (p < 2 ? a[2 * p] : b2[2 * p - 4]);
          const float xi = (p < 2 ? a[2 * p + 1] : b2[2 * p - 3]);
          fr.h2[p] = __builtin_amdgcn_cvt_pkrtz((xr * cv[p] - xi * sv[p]) * LOG2E,
                                                (xr * sv[p] + xi * cv[p]) * LOG2E);
        }
        qfrag[dblk] = fr.v;
      }
    }

    const f32x16 zf = {};
    f32x16 acc[8];                                // O^T: col=vcol(l31), rows=q
#pragma unroll
    for (int g = 0; g < 8; ++g) acc[g] = zf;
    float mrun = -1e30f;                          // per-lane (its q), log2 domain
    float lrun = 0.f;                             // per-lane partial denominator

    const int nkt = 4 * (qt + 1);

    for (int kt = 0; kt < nkt; ++kt) {
      const int ktb = kt * KT;
      // ---- stage K tile with RoPE -> Klds[buf]; chunks {kt8, kt8+8}, slot = c^(kr&7) ----
      {
        const int krow = ktb + kr;
        const float* kpb = xk + (row0 + krow) * (size_t)(NHEAD * ZDIM) + h * ZDIM;
        const float* ckb = cosT + krow * (ZDIM / 2);
        const float* skb = sinT + krow * (ZDIM / 2);
        f32x4 a0 = *(const f32x4*)(kpb + 8 * kt8);
        f32x4 a1 = *(const f32x4*)(kpb + 8 * kt8 + 4);
        f32x4 ca = *(const f32x4*)(ckb + 4 * kt8);
        f32x4 sa = *(const f32x4*)(skb + 4 * kt8);
        f32x4 b0 = *(const f32x4*)(kpb + 8 * kt8 + 64);
        f32x4 b1 = *(const f32x4*)(kpb + 8 * kt8 + 68);
        f32x4 cbv = *(const f32x4*)(ckb + 4 * kt8 + 32);
        f32x4 sbv = *(const f32x4*)(skb + 4 * kt8 + 32);
        union { h16x2 h2[4]; f16x8 v; } koA, koB;
#pragma unroll
        for (int p = 0; p < 4; ++p) {
          const float xrA = (p < 2 ? a0[2 * p] : a1[2 * p - 4]);
          const float xiA = (p < 2 ? a0[2 * p + 1] : a1[2 * p - 3]);
          koA.h2[p] = __builtin_amdgcn_cvt_pkrtz(xrA * ca[p] - xiA * sa[p],
                                                 xrA * sa[p] + xiA * ca[p]);
          const float xrB = (p < 2 ? b0[2 * p] : b1[2 * p - 4]);
          const float xiB = (p < 2 ? b0[2 * p + 1] : b1[2 * p - 3]);
          koB.h2[p] = __builtin_amdgcn_cvt_pkrtz(xrB * cbv[p] - xiB * sbv[p],
                                                 xrB * sbv[p] + xiB * cbv[p]);
        }
        const int sw = kr & 7;
        *(f16x8*)&Klds[buf][kr * KSTRIDE + ((kt8 ^ sw) * 8)]       = koA.v;
        *(f16x8*)&Klds[buf][kr * KSTRIDE + (((kt8 + 8) ^ sw) * 8)] = koB.v;
      }
      // ---- stage V tile transposed -> Vlds[buf] (kblk^vsw, inb^vflip) ----
      {
        const int vrow = ktb + vg * 4;
        const float* vp = xv + (row0 + vrow) * (size_t)(NHEAD * VDIM) + h * VDIM + vc0;
        f32x4 v0 = *(const f32x4*)(vp);         f32x4 v1 = *(const f32x4*)(vp + 4);
        f32x4 v2 = *(const f32x4*)(vp + 2048);  f32x4 v3 = *(const f32x4*)(vp + 2052);
        f32x4 v4 = *(const f32x4*)(vp + 4096);  f32x4 v5 = *(const f32x4*)(vp + 4100);
        f32x4 v6 = *(const f32x4*)(vp + 6144);  f32x4 v7 = *(const f32x4*)(vp + 6148);
#pragma unroll
        for (int ci = 0; ci < 8; ++ci) {
          const float e0 = (ci < 4 ? v0[ci] : v1[ci - 4]);
          const float e1 = (ci < 4 ? v2[ci] : v3[ci - 4]);
          const float e2 = (ci < 4 ? v4[ci] : v5[ci - 4]);
          const float e3 = (ci < 4 ? v6[ci] : v7[ci - 4]);
          union { h16x2 a2[2]; f16x4 v; } t;
          t.a2[0] = __builtin_amdgcn_cvt_pkrtz(e0, e1);
          t.a2[1] = __builtin_amdgcn_cvt_pkrtz(e2, e3);
          *(f16x4*)&Vlds[buf][(vc0 + ci) * VSTRIDE + ((kblk ^ vsw) * 8) + (inb ^ vflip)] = t.v;
        }
      }
      __syncthreads();   // staging visible; dbuf makes one barrier/tile safe

      // ---- per-wave skip of fully-masked tiles ----
      if (ktb <= wq0 + 31) {
        // ---- S^T = K Q : col=l31=q, row=k-local ----
        f32x16 s = {};
        __builtin_amdgcn_s_setprio(1);
#pragma unroll
        for (int dblk = 0; dblk < 8; ++dblk) {
          f16x8 kf = *(const f16x8*)&Klds[buf][l31 * KSTRIDE + (((dblk * 2 + hi) ^ kswz) * 8)];
          s = __builtin_amdgcn_mfma_f32_32x32x16_f16(kf, qfrag[dblk], s, 0, 0, 0);
        }
        __builtin_amdgcn_s_setprio(0);

        // ---- causal mask (partial tiles only); k_local = (r&3)+8*(r>>2)+4*hi ----
        if (ktb + 31 > wq0) {
#pragma unroll
          for (int r = 0; r < 16; ++r) {
            const int kg = ktb + ((r & 3) + 8 * (r >> 2) + 4 * hi);
            if (kg > qg) s[r] = -1.0e9f;
          }
        }

        // ---- softmax: lane-local max + one cross-half shuffle ----
        float m = s[0];
#pragma unroll
        for (int r = 1; r < 16; ++r) m = fmaxf(m, s[r]);
        m = fmaxf(m, __shfl_xor(m, 32));
        const bool need = (m > mrun + RTHR);
        if (__any(need)) {
          const float Mn = fmaxf(mrun, m);
          const float al = exp2f(mrun - Mn);
          mrun = Mn;
          lrun *= al;
#pragma unroll
          for (int r = 0; r < 16; ++r) {
            const float alr = __shfl(al, (r & 3) + 8 * (r >> 2) + 4 * hi);
#pragma unroll
            for (int g = 0; g < 8; ++g) acc[g][r] *= alr;
          }
        }
        float pr[16];
        float lsum = 0.f;
#pragma unroll
        for (int r = 0; r < 16; ++r) {
          pr[r] = exp2f(s[r] - mrun);
          lsum += pr[r];
        }
        lrun += lsum;

        // ---- P -> fp16 A-frags in registers, then PV ----
#pragma unroll
        for (int kb = 0; kb < 2; ++kb) {
          union { h16x2 h; u32 u; } A_, B_, C_, D_;
          A_.h = __builtin_amdgcn_cvt_pkrtz(pr[8 * kb + 0], pr[8 * kb + 1]);
          B_.h = __builtin_amdgcn_cvt_pkrtz(pr[8 * kb + 2], pr[8 * kb + 3]);
          C_.h = __builtin_amdgcn_cvt_pkrtz(pr[8 * kb + 4], pr[8 * kb + 5]);
          D_.h = __builtin_amdgcn_cvt_pkrtz(pr[8 * kb + 6], pr[8 * kb + 7]);
          const u32 G1 = hi ? A_.u : C_.u;
          const u32 G2 = hi ? B_.u : D_.u;
          const u32 G1s = (u32)__shfl_xor((int)G1, 32);
          const u32 G2s = (u32)__shfl_xor((int)G2, 32);
          union { u32 u[4]; f16x8 v; } af;
          af.u[0] = hi ? G1s : A_.u;
          af.u[1] = hi ? G2s : B_.u;
          af.u[2] = hi ? C_.u : G1s;
          af.u[3] = hi ? D_.u : G2s;
          __builtin_amdgcn_s_setprio(1);
#pragma unroll
          for (int g = 0; g < 8; ++g) {
            const int vcol = g * 32 + l31;
            const int ck = (((kb * 2 + hi) ^ vswz) * 8);
            const int fl = (g & 1) * 4;   // matches write-side (vcol>>5)&1
            union { f16x4 h4[2]; f16x8 v; } bf;
            bf.h4[0] = *(const f16x4*)&Vlds[buf][vcol * VSTRIDE + ck + fl];
            bf.h4[1] = *(const f16x4*)&Vlds[buf][vcol * VSTRIDE + ck + (fl ^ 4)];
            acc[g] = __builtin_amdgcn_mfma_f32_32x32x16_f16(af.v, bf.v, acc[g], 0, 0, 0);
          }
          __builtin_amdgcn_s_setprio(0);
        }
      }
      buf ^= 1;
    }

    // ---- epilogue: denom reduce (1 shuffle), per-row linv broadcast, store ----
    const float ls = lrun + __shfl_xor(lrun, 32);
    const float linv = 1.0f / ls;
#pragma unroll
    for (int r = 0; r < 16; ++r) {
      const int qloc = (r & 3) + 8 * (r >> 2) + 4 * hi;
      const float lr = __shfl(linv, qloc);
      const size_t ob = (row0 + wq0 + qloc) * (size_t)(NHEAD * VDIM) + h * VDIM + l31;
#pragma unroll
      for (int g = 0; g < 8; ++g)
        out[ob + g * 32] = acc[g][r] * lr;
    }
    __syncthreads();   // half boundary safety
  }
}

extern "C" void kernel_launch(void* const* d_in, const int* in_sizes, int n_in,
                              void* d_out, int out_size, void* d_ws, size_t ws_size,
                              hipStream_t stream) {
  const float* xq   = (const float*)d_in[0];
  const float* xk   = (const float*)d_in[1];
  const float* xv   = (const float*)d_in[2];
  // d_in[3] = mask (unused: causal mask computed analytically)
  const float* cosT = (const float*)d_in[4];
  const float* sinT = (const float*)d_in[5];
  float* out = (float*)d_out;

  dim3 grid(512);    // (4 qpairs) x (128 chunk*head), XCD-swizzled, 2 blocks/CU
  dim3 block(256);   // 4 waves
  attn_fused<<<grid, block, 0, stream>>>(xq, xk, xv, cosT, sinT, out);
}